// Round 1
// baseline (221.527 us; speedup 1.0000x reference)
//
#include <hip/hip_runtime.h>
#include <stdint.h>

#define A_TOTAL 43008
#define NB 16
#define NM 128
#define MCOL 4

// key = (iou_bits << 32) | (0xFFFFFFFF - anchor_idx)
// max(key) == max IoU, first (smallest) anchor index on ties — jnp.argmax semantics.
__device__ __forceinline__ unsigned long long pack_key(float iou, unsigned int a) {
    unsigned int bits = __float_as_uint(iou);  // iou >= 0 -> bits monotone
    return ((unsigned long long)bits << 32) | (unsigned long long)(0xFFFFFFFFu - a);
}

__device__ __forceinline__ unsigned long long shfl_down_u64(unsigned long long v, int off) {
    unsigned int lo = (unsigned int)v;
    unsigned int hi = (unsigned int)(v >> 32);
    lo = __shfl_down(lo, off, 64);
    hi = __shfl_down(hi, off, 64);
    return ((unsigned long long)hi << 32) | (unsigned long long)lo;
}

// Per-bbox (column) max/argmax of IoU over all anchors.
// grid = (NM/MCOL, NB), block = 256. Each block handles MCOL boxes of one batch.
__global__ __launch_bounds__(256) void cols_kernel(
    const float4* __restrict__ anchors, const float4* __restrict__ bboxes,
    float* __restrict__ colmax, int* __restrict__ colarg) {
#pragma clang fp contract(off)
    const int b  = blockIdx.y;
    const int m0 = blockIdx.x * MCOL;
    const int tid = threadIdx.x;

    __shared__ float4 sbox[MCOL];
    if (tid < MCOL) sbox[tid] = bboxes[b * NM + m0 + tid];
    __syncthreads();

    float bx1[MCOL], by1[MCOL], bx2[MCOL], by2[MCOL], areaB[MCOL];
#pragma unroll
    for (int k = 0; k < MCOL; ++k) {
        float4 v = sbox[k];
        bx1[k] = v.x; by1[k] = v.y; bx2[k] = v.z; by2[k] = v.w;
        areaB[k] = (v.z - v.x) * (v.w - v.y);
    }

    unsigned long long best[MCOL];
#pragma unroll
    for (int k = 0; k < MCOL; ++k) best[k] = 0ull;

    for (int a = tid; a < A_TOTAL; a += 256) {
        float4 an = anchors[a];                       // cx, cy, w, h
        float hw = an.z * 0.5f, hh = an.w * 0.5f;
        float ax1 = an.x - hw, ay1 = an.y - hh;
        float ax2 = an.x + hw, ay2 = an.y + hh;
        float areaA = (ax2 - ax1) * (ay2 - ay1);
#pragma unroll
        for (int k = 0; k < MCOL; ++k) {
            float ltx = fmaxf(ax1, bx1[k]), lty = fmaxf(ay1, by1[k]);
            float rbx = fminf(ax2, bx2[k]), rby = fminf(ay2, by2[k]);
            float wx = fmaxf(rbx - ltx, 0.0f), wy = fmaxf(rby - lty, 0.0f);
            float inter = wx * wy;
            float iou = inter / ((areaA + areaB[k]) - inter);
            unsigned long long key = pack_key(iou, (unsigned int)a);
            if (key > best[k]) best[k] = key;
        }
    }

    __shared__ unsigned long long red[4][MCOL];
    const int lane = tid & 63, wv = tid >> 6;
#pragma unroll
    for (int k = 0; k < MCOL; ++k) {
        unsigned long long v = best[k];
        for (int off = 32; off > 0; off >>= 1) {
            unsigned long long o = shfl_down_u64(v, off);
            if (o > v) v = o;
        }
        if (lane == 0) red[wv][k] = v;
    }
    __syncthreads();
    if (tid < MCOL) {
        unsigned long long v = red[0][tid];
        for (int w = 1; w < 4; ++w) if (red[w][tid] > v) v = red[w][tid];
        colmax[b * NM + m0 + tid] = __uint_as_float((unsigned int)(v >> 32));
        colarg[b * NM + m0 + tid] = (int)(0xFFFFFFFFu - (unsigned int)(v & 0xFFFFFFFFull));
    }
}

// Per-anchor (row) max/argmax + override + score + matched gather.
// grid = (A_TOTAL/256, NB), block = 256. One thread per (b, anchor).
__global__ __launch_bounds__(256) void rows_final_kernel(
    const float4* __restrict__ anchors, const float4* __restrict__ bboxes,
    const int* __restrict__ labels, const float* __restrict__ colmax,
    const int* __restrict__ colarg, float* __restrict__ out_scores,
    float4* __restrict__ out_matched) {
#pragma clang fp contract(off)
    const int b = blockIdx.y;
    const int tid = threadIdx.x;
    const int a = blockIdx.x * 256 + tid;   // A_TOTAL == 168*256, no remainder

    __shared__ float4 sbox[NM];
    __shared__ float  s_area[NM];
    __shared__ float  s_cm[NM];
    __shared__ int    s_ca[NM];
    __shared__ int    s_lab[NM];
    if (tid < NM) {
        float4 v = bboxes[b * NM + tid];
        sbox[tid]   = v;
        s_area[tid] = (v.z - v.x) * (v.w - v.y);
        s_cm[tid]   = colmax[b * NM + tid];
        s_ca[tid]   = colarg[b * NM + tid];
        s_lab[tid]  = labels[b * NM + tid];
    }
    __syncthreads();

    float4 an = anchors[a];
    float hw = an.z * 0.5f, hh = an.w * 0.5f;
    float ax1 = an.x - hw, ay1 = an.y - hh;
    float ax2 = an.x + hw, ay2 = an.y + hh;
    float areaA = (ax2 - ax1) * (ay2 - ay1);

    float best = -1.0f; int bi = 0;    // strict > keeps first occurrence (argmax)
    for (int m = 0; m < NM; ++m) {
        float4 v = sbox[m];
        float ltx = fmaxf(ax1, v.x), lty = fmaxf(ay1, v.y);
        float rbx = fminf(ax2, v.z), rby = fminf(ay2, v.w);
        float wx = fmaxf(rbx - ltx, 0.0f), wy = fmaxf(rby - lty, 0.0f);
        float inter = wx * wy;
        float iou = inter / ((areaA + s_area[m]) - inter);
        if (iou > best) { best = iou; bi = m; }
    }

    // Sequential override "later gt wins" == largest j with anchor_indice[j] == a.
    for (int j = NM - 1; j >= 0; --j) {
        if (s_ca[j] == a) { bi = j; best = s_cm[j]; break; }
    }

    float denom = fmaxf(s_cm[bi], 0.3f);               // IOU_THR
    float val   = (best < 0.15f) ? 0.0f : best;        // IOU_THR * 0.5
    float score = val / denom;
    if (s_lab[bi] <= 0) score = 0.0f;

    out_scores[(size_t)b * A_TOTAL + a] = score;
    out_matched[(size_t)b * A_TOTAL + a] = sbox[bi];
}

extern "C" void kernel_launch(void* const* d_in, const int* in_sizes, int n_in,
                              void* d_out, int out_size, void* d_ws, size_t ws_size,
                              hipStream_t stream) {
    const int*    labels  = (const int*)d_in[0];     // [NB, NM] int32
    const float4* bboxes  = (const float4*)d_in[1];  // [NB, NM, 4] xyxy
    const float4* anchors = (const float4*)d_in[2];  // [A_TOTAL, 4] cxcywh

    float* out = (float*)d_out;                      // scores [NB,A] then matched [NB,A,4]
    float* colmax = (float*)d_ws;                    // NB*NM floats
    int*   colarg = (int*)((char*)d_ws + (size_t)NB * NM * sizeof(float));

    dim3 gA(NM / MCOL, NB);
    cols_kernel<<<gA, 256, 0, stream>>>(anchors, bboxes, colmax, colarg);

    dim3 gB(A_TOTAL / 256, NB);
    rows_final_kernel<<<gB, 256, 0, stream>>>(
        anchors, bboxes, labels, colmax, colarg,
        out, (float4*)(out + (size_t)NB * A_TOTAL));
}

// Round 2
// 183.419 us; speedup vs baseline: 1.2078x; 1.2078x over previous
//
#include <hip/hip_runtime.h>
#include <stdint.h>

typedef unsigned long long u64;

#define A_TOTAL 43008
#define NB 16
#define NM 128
#define SPLIT 84                         // blocks per batch (fused kernel)
#define WPB 4                            // waves per block
#define APW (A_TOTAL / (SPLIT * WPB))    // 128 anchors per wave

// ---------------------------------------------------------------------------
// Fused kernel: one pass over the IoU matrix computes BOTH reductions.
//  - col (per-box) max/argmax: 2 boxes/lane live in registers; running packed
//    key (iou_bits<<32)|(~anchor) -> max == max iou, ties -> smallest anchor.
//  - row (per-anchor) max/argmax: wave-wide float max via shfl_xor, then
//    first-index via ballot+ffsll (jnp.argmax first-occurrence semantics).
// grid (SPLIT, NB), block 256 (4 waves). Each wave owns APW consecutive anchors.
// ---------------------------------------------------------------------------
__global__ __launch_bounds__(256) void fused_kernel(
    const float4* __restrict__ anchors, const float4* __restrict__ bboxes,
    u64* __restrict__ rowkey,        // [NB][A_TOTAL]  (iou_bits<<32)|m
    u64* __restrict__ colpart) {     // [NB][SPLIT][NM] packed col keys
#pragma clang fp contract(off)
    const int b    = blockIdx.y;
    const int tid  = threadIdx.x;
    const int lane = tid & 63;
    const int wv   = tid >> 6;
    const int base = (blockIdx.x * WPB + wv) * APW;

    float4 box0 = bboxes[b * NM + lane];        // m = lane
    float4 box1 = bboxes[b * NM + lane + 64];   // m = lane + 64
    float areaB0 = (box0.z - box0.x) * (box0.w - box0.y);
    float areaB1 = (box1.z - box1.x) * (box1.w - box1.y);

    u64 ck0 = 0ull, ck1 = 0ull;

    for (int g = 0; g < APW / 64; ++g) {
        u64 keep = 0ull;
#pragma unroll 2
        for (int i = 0; i < 64; ++i) {
            const int a = base + g * 64 + i;
            float4 an = anchors[a];              // wave-uniform -> broadcast
            float hw = an.z * 0.5f, hh = an.w * 0.5f;
            float ax1 = an.x - hw, ay1 = an.y - hh;
            float ax2 = an.x + hw, ay2 = an.y + hh;
            float areaA = (ax2 - ax1) * (ay2 - ay1);

            float ltx0 = fmaxf(ax1, box0.x), lty0 = fmaxf(ay1, box0.y);
            float rbx0 = fminf(ax2, box0.z), rby0 = fminf(ay2, box0.w);
            float wx0 = fmaxf(rbx0 - ltx0, 0.0f), wy0 = fmaxf(rby0 - lty0, 0.0f);
            float in0 = wx0 * wy0;
            float iou0 = in0 / ((areaA + areaB0) - in0);

            float ltx1 = fmaxf(ax1, box1.x), lty1 = fmaxf(ay1, box1.y);
            float rbx1 = fminf(ax2, box1.z), rby1 = fminf(ay2, box1.w);
            float wx1 = fmaxf(rbx1 - ltx1, 0.0f), wy1 = fmaxf(rby1 - lty1, 0.0f);
            float in1 = wx1 * wy1;
            float iou1 = in1 / ((areaA + areaB1) - in1);

            // column (per-box) running max, ties -> smaller anchor index
            u64 k0 = ((u64)__float_as_uint(iou0) << 32) | (u64)(0xFFFFFFFFu - (unsigned)a);
            u64 k1 = ((u64)__float_as_uint(iou1) << 32) | (u64)(0xFFFFFFFFu - (unsigned)a);
            if (k0 > ck0) ck0 = k0;
            if (k1 > ck1) ck1 = k1;

            // row (per-anchor) max over all 128 boxes held by this wave
            float v = fmaxf(iou0, iou1);
            for (int off = 1; off < 64; off <<= 1)
                v = fmaxf(v, __shfl_xor(v, off, 64));
            u64 mask0 = __ballot(iou0 == v);     // candidates m = lane
            u64 mask1 = __ballot(iou1 == v);     // candidates m = lane + 64
            int m = mask0 ? (__ffsll(mask0) - 1) : (__ffsll(mask1) + 63);
            u64 rk = ((u64)__float_as_uint(v) << 32) | (u64)(unsigned)m;
            if (i == lane) keep = rk;            // lane i keeps anchor i's result
        }
        // fully coalesced 64-lane store of this group's row results
        rowkey[(size_t)b * A_TOTAL + base + g * 64 + lane] = keep;
    }

    // block-level column reduce across the 4 waves
    __shared__ u64 scol[WPB][NM];
    scol[wv][lane]      = ck0;
    scol[wv][lane + 64] = ck1;
    __syncthreads();
    if (tid < NM) {
        u64 k = scol[0][tid];
        for (int w = 1; w < WPB; ++w) { u64 o = scol[w][tid]; if (o > k) k = o; }
        colpart[((size_t)b * SPLIT + blockIdx.x) * NM + tid] = k;
    }
}

// Final column reduce across SPLIT blocks. grid(NB), block(NM).
__global__ __launch_bounds__(NM) void colreduce_kernel(
    const u64* __restrict__ colpart,
    float* __restrict__ colmax, int* __restrict__ colarg) {
    const int b = blockIdx.x, m = threadIdx.x;
    u64 k = 0ull;
    for (int s = 0; s < SPLIT; ++s) {
        u64 o = colpart[((size_t)b * SPLIT + s) * NM + m];
        if (o > k) k = o;
    }
    colmax[b * NM + m] = __uint_as_float((unsigned)(k >> 32));
    colarg[b * NM + m] = (int)(0xFFFFFFFFu - (unsigned)(k & 0xFFFFFFFFull));
}

// Per-anchor override + score + matched gather. grid (A/256, NB), block 256.
__global__ __launch_bounds__(256) void epilogue_kernel(
    const float4* __restrict__ bboxes, const int* __restrict__ labels,
    const float* __restrict__ colmax, const int* __restrict__ colarg,
    const u64* __restrict__ rowkey,
    float* __restrict__ out_scores, float4* __restrict__ out_matched) {
    const int b = blockIdx.y, tid = threadIdx.x;
    const int a = blockIdx.x * 256 + tid;      // A_TOTAL == 168*256

    __shared__ float4 sbox[NM];
    __shared__ float  s_cm[NM];
    __shared__ int    s_ca[NM];
    __shared__ int    s_lab[NM];
    if (tid < NM) {
        sbox[tid]  = bboxes[b * NM + tid];
        s_cm[tid]  = colmax[b * NM + tid];
        s_ca[tid]  = colarg[b * NM + tid];
        s_lab[tid] = labels[b * NM + tid];
    }
    __syncthreads();

    u64 rk = rowkey[(size_t)b * A_TOTAL + a];
    float best = __uint_as_float((unsigned)(rk >> 32));
    int   bi   = (int)(rk & 0xFFFFFFFFull);

    // sequential "later gt wins" override == last j (ascending) with colarg[j]==a
#pragma unroll
    for (int j = 0; j < NM; ++j) {
        bool hit = (s_ca[j] == a);
        bi   = hit ? j : bi;
        best = hit ? s_cm[j] : best;
    }

    float denom = fmaxf(s_cm[bi], 0.3f);       // IOU_THR
    float val   = (best < 0.15f) ? 0.0f : best; // IOU_THR * 0.5
    float score = val / denom;
    if (s_lab[bi] <= 0) score = 0.0f;

    out_scores[(size_t)b * A_TOTAL + a]  = score;
    out_matched[(size_t)b * A_TOTAL + a] = sbox[bi];
}

extern "C" void kernel_launch(void* const* d_in, const int* in_sizes, int n_in,
                              void* d_out, int out_size, void* d_ws, size_t ws_size,
                              hipStream_t stream) {
    const int*    labels  = (const int*)d_in[0];     // [NB, NM] int32
    const float4* bboxes  = (const float4*)d_in[1];  // [NB, NM, 4] xyxy
    const float4* anchors = (const float4*)d_in[2];  // [A_TOTAL, 4] cxcywh

    float* out = (float*)d_out;                      // scores [NB,A], matched [NB,A,4]

    char* ws = (char*)d_ws;
    u64*   rowkey  = (u64*)ws;                                   ws += (size_t)NB * A_TOTAL * sizeof(u64);
    u64*   colpart = (u64*)ws;                                   ws += (size_t)NB * SPLIT * NM * sizeof(u64);
    float* colmax  = (float*)ws;                                 ws += (size_t)NB * NM * sizeof(float);
    int*   colarg  = (int*)ws;

    dim3 gF(SPLIT, NB);
    fused_kernel<<<gF, 256, 0, stream>>>(anchors, bboxes, rowkey, colpart);

    colreduce_kernel<<<NB, NM, 0, stream>>>(colpart, colmax, colarg);

    dim3 gE(A_TOTAL / 256, NB);
    epilogue_kernel<<<gE, 256, 0, stream>>>(
        bboxes, labels, colmax, colarg, rowkey,
        out, (float4*)(out + (size_t)NB * A_TOTAL));
}

// Round 3
// 166.873 us; speedup vs baseline: 1.3275x; 1.0992x over previous
//
#include <hip/hip_runtime.h>
#include <stdint.h>

typedef unsigned long long u64;

#define A_TOTAL 43008
#define NB 16
#define NM 128
#define SPLIT 168                 // blocks per batch (fused kernel)
#define WPB 4                     // waves per block; each wave owns 64 anchors

// f32 max with cross-lane DPP partner; invalid lanes fall back to src (identity).
#define DPPMAX(v, ctrl)                                                          \
  fmaxf(v, __int_as_float(__builtin_amdgcn_update_dpp(                           \
               __float_as_int(v), __float_as_int(v), ctrl, 0xF, 0xF, false)))

__device__ __forceinline__ float wave_max_f32(float v) {
    v = DPPMAX(v, 0xB1);   // quad_perm [1,0,3,2]  : xor 1
    v = DPPMAX(v, 0x4E);   // quad_perm [2,3,0,1]  : xor 2
    v = DPPMAX(v, 0x141);  // row_half_mirror      : xor 4
    v = DPPMAX(v, 0x140);  // row_mirror           : xor 8
    v = fmaxf(v, __int_as_float(
            __builtin_amdgcn_ds_swizzle(__float_as_int(v), 0x401F))); // xor 16
    v = fmaxf(v, __shfl_xor(v, 32, 64));                              // xor 32
    return v;
}

// Precompute anchors: cxcywh -> xyxy + area (batch-independent).
__global__ __launch_bounds__(256) void prep_kernel(
    const float4* __restrict__ anchors, float4* __restrict__ apre,
    float* __restrict__ aarea) {
#pragma clang fp contract(off)
    const int a = blockIdx.x * 256 + threadIdx.x;     // 168 blocks
    float4 an = anchors[a];
    float hw = an.z * 0.5f, hh = an.w * 0.5f;
    float x1 = an.x - hw, y1 = an.y - hh, x2 = an.x + hw, y2 = an.y + hh;
    apre[a] = make_float4(x1, y1, x2, y2);
    aarea[a] = (x2 - x1) * (y2 - y1);
}

// One pass over the IoU matrix, both reductions.
// Lanes own the 128 boxes (2/lane); anchors are wave-uniform (SGPR loads).
// Row (per-anchor) max: DPP butterfly + ballot first-index (jnp tie semantics).
// Col (per-box) max: per-lane float cmp; ascending anchor order => strict '>'
// keeps the smallest anchor index on exact ties.
__global__ __launch_bounds__(256) void fused_kernel(
    const float4* __restrict__ apre, const float* __restrict__ aarea,
    const float4* __restrict__ bboxes,
    float* __restrict__ rowv, unsigned char* __restrict__ rowm,
    u64* __restrict__ colpart) {
#pragma clang fp contract(off)
    const int b = blockIdx.y;
    const int tid = threadIdx.x;
    const int lane = tid & 63, wv = tid >> 6;
    const int base = (blockIdx.x * WPB + wv) * 64;

    float4 b0 = bboxes[b * NM + lane];          // m = lane
    float4 b1 = bboxes[b * NM + lane + 64];     // m = lane + 64
    float areaB0 = (b0.z - b0.x) * (b0.w - b0.y);
    float areaB1 = (b1.z - b1.x) * (b1.w - b1.y);

    float cv0 = -1.0f, cv1 = -1.0f;
    int ca0 = 0, ca1 = 0;
    float keep_v = 0.0f;
    int keep_m = 0;

#pragma unroll 4
    for (int i = 0; i < 64; ++i) {
        const int a = base + i;                  // wave-uniform
        const float4 ap = apre[a];               // scalar loads
        const float areaA = aarea[a];

        float ltx0 = fmaxf(ap.x, b0.x), lty0 = fmaxf(ap.y, b0.y);
        float rbx0 = fminf(ap.z, b0.z), rby0 = fminf(ap.w, b0.w);
        float wx0 = fmaxf(rbx0 - ltx0, 0.0f), wy0 = fmaxf(rby0 - lty0, 0.0f);
        float in0 = wx0 * wy0;
        float iou0 = in0 / ((areaA + areaB0) - in0);

        float ltx1 = fmaxf(ap.x, b1.x), lty1 = fmaxf(ap.y, b1.y);
        float rbx1 = fminf(ap.z, b1.z), rby1 = fminf(ap.w, b1.w);
        float wx1 = fmaxf(rbx1 - ltx1, 0.0f), wy1 = fmaxf(rby1 - lty1, 0.0f);
        float in1 = wx1 * wy1;
        float iou1 = in1 / ((areaA + areaB1) - in1);

        if (iou0 > cv0) { cv0 = iou0; ca0 = a; }
        if (iou1 > cv1) { cv1 = iou1; ca1 = a; }

        float v = wave_max_f32(fmaxf(iou0, iou1));
        u64 m0 = __ballot(iou0 == v);            // candidates m = lane
        u64 m1 = __ballot(iou1 == v);            // candidates m = lane + 64
        int m = m0 ? (__ffsll((long long)m0) - 1) : (__ffsll((long long)m1) + 63);

        bool me = (lane == i);
        keep_v = me ? v : keep_v;
        keep_m = me ? m : keep_m;
    }
    rowv[(size_t)b * A_TOTAL + base + lane] = keep_v;
    rowm[(size_t)b * A_TOTAL + base + lane] = (unsigned char)keep_m;

    // block-level column reduce across the 4 waves (ascending anchor ranges)
    __shared__ float scv[WPB][NM];
    __shared__ int   sca[WPB][NM];
    scv[wv][lane] = cv0;       sca[wv][lane] = ca0;
    scv[wv][lane + 64] = cv1;  sca[wv][lane + 64] = ca1;
    __syncthreads();
    if (tid < NM) {
        float bv = scv[0][tid]; int ba = sca[0][tid];
        for (int w = 1; w < WPB; ++w) {
            float ov = scv[w][tid];
            if (ov > bv) { bv = ov; ba = sca[w][tid]; }
        }
        u64 key = ((u64)__float_as_uint(bv) << 32) |
                  (u64)(0xFFFFFFFFu - (unsigned)ba);
        colpart[((size_t)b * SPLIT + blockIdx.x) * NM + tid] = key;
    }
}

// Final col reduce + build the override table (later j wins == sequential scan).
// grid(NB), block(NM).
__global__ __launch_bounds__(NM) void colreduce_kernel(
    const u64* __restrict__ colpart, float* __restrict__ colmax,
    int* __restrict__ colarg, unsigned short* __restrict__ tbl) {
    const int b = blockIdx.x, m = threadIdx.x;
    u64 k = 0ull;
    for (int s = 0; s < SPLIT; ++s) {
        u64 o = colpart[((size_t)b * SPLIT + s) * NM + m];
        if (o > k) k = o;
    }
    colmax[b * NM + m] = __uint_as_float((unsigned)(k >> 32));
    int ca = (int)(0xFFFFFFFFu - (unsigned)(k & 0xFFFFFFFFull));
    colarg[b * NM + m] = ca;

    __shared__ int sca[NM];
    sca[m] = ca;
    __syncthreads();
    if (m == 0) {
        for (int j = 0; j < NM; ++j)          // program order: later j overwrites
            tbl[(size_t)b * A_TOTAL + sca[j]] = (unsigned short)j;
    }
}

// Streaming epilogue: override lookup + score + matched gather.
__global__ __launch_bounds__(256) void epilogue_kernel(
    const float4* __restrict__ bboxes, const int* __restrict__ labels,
    const float* __restrict__ colmax,
    const float* __restrict__ rowv, const unsigned char* __restrict__ rowm,
    const unsigned short* __restrict__ tbl,
    float* __restrict__ out_scores, float4* __restrict__ out_matched) {
#pragma clang fp contract(off)
    const int b = blockIdx.y, tid = threadIdx.x;
    const int a = blockIdx.x * 256 + tid;       // A_TOTAL == 168*256

    __shared__ float4 sbox[NM];
    __shared__ float  s_cm[NM];
    __shared__ int    s_lab[NM];
    if (tid < NM) {
        sbox[tid]  = bboxes[b * NM + tid];
        s_cm[tid]  = colmax[b * NM + tid];
        s_lab[tid] = labels[b * NM + tid];
    }
    __syncthreads();

    float best = rowv[(size_t)b * A_TOTAL + a];
    int   bi   = rowm[(size_t)b * A_TOTAL + a];
    unsigned short j = tbl[(size_t)b * A_TOTAL + a];
    if (j != 0xFFFFu) { bi = j; best = s_cm[j]; }

    float denom = fmaxf(s_cm[bi], 0.3f);        // IOU_THR
    float val   = (best < 0.15f) ? 0.0f : best; // IOU_THR * 0.5
    float score = val / denom;
    if (s_lab[bi] <= 0) score = 0.0f;

    out_scores[(size_t)b * A_TOTAL + a]  = score;
    out_matched[(size_t)b * A_TOTAL + a] = sbox[bi];
}

extern "C" void kernel_launch(void* const* d_in, const int* in_sizes, int n_in,
                              void* d_out, int out_size, void* d_ws, size_t ws_size,
                              hipStream_t stream) {
    const int*    labels  = (const int*)d_in[0];     // [NB, NM] int32
    const float4* bboxes  = (const float4*)d_in[1];  // [NB, NM, 4] xyxy
    const float4* anchors = (const float4*)d_in[2];  // [A_TOTAL, 4] cxcywh

    float* out = (float*)d_out;                      // scores [NB,A], matched [NB,A,4]

    char* ws = (char*)d_ws;
    float4* apre   = (float4*)ws;                         ws += (size_t)A_TOTAL * 16;
    u64*    colpart= (u64*)ws;                            ws += (size_t)NB * SPLIT * NM * 8;
    float*  rowv   = (float*)ws;                          ws += (size_t)NB * A_TOTAL * 4;
    float*  aarea  = (float*)ws;                          ws += (size_t)A_TOTAL * 4;
    float*  colmax = (float*)ws;                          ws += (size_t)NB * NM * 4;
    int*    colarg = (int*)ws;                            ws += (size_t)NB * NM * 4;
    unsigned short* tbl = (unsigned short*)ws;            ws += (size_t)NB * A_TOTAL * 2;
    unsigned char* rowm = (unsigned char*)ws;

    prep_kernel<<<A_TOTAL / 256, 256, 0, stream>>>(anchors, apre, aarea);
    hipMemsetAsync(tbl, 0xFF, (size_t)NB * A_TOTAL * 2, stream);  // sentinel 0xFFFF

    dim3 gF(SPLIT, NB);
    fused_kernel<<<gF, 256, 0, stream>>>(apre, aarea, bboxes, rowv, rowm, colpart);

    colreduce_kernel<<<NB, NM, 0, stream>>>(colpart, colmax, colarg, tbl);

    dim3 gE(A_TOTAL / 256, NB);
    epilogue_kernel<<<gE, 256, 0, stream>>>(
        bboxes, labels, colmax, rowv, rowm, tbl,
        out, (float4*)(out + (size_t)NB * A_TOTAL));
}

// Round 4
// 155.367 us; speedup vs baseline: 1.4258x; 1.0741x over previous
//
#include <hip/hip_runtime.h>
#include <stdint.h>

typedef unsigned long long u64;

#define A_TOTAL 43008
#define NB 16
#define NM 128
#define SPLIT 168                 // blocks per batch; 4 waves/block; 64 anchors/wave
#define WPB 4
#define CHUNK 8                   // anchors per row-reduce chunk
#define NCH 8                     // chunks per wave (64 anchors)

// u64 cross-lane via two 32-bit DPP moves (identity fallback, all rows/banks).
__device__ __forceinline__ u64 dpp_u64(u64 v, const int ctrl) {
    int lo = (int)(unsigned)v, hi = (int)(unsigned)(v >> 32);
    int plo, phi;
    switch (ctrl) {  // ctrl must be a literal constant for the builtin
        case 0xB1:
            plo = __builtin_amdgcn_update_dpp(lo, lo, 0xB1, 0xF, 0xF, false);
            phi = __builtin_amdgcn_update_dpp(hi, hi, 0xB1, 0xF, 0xF, false);
            break;
        case 0x4E:
            plo = __builtin_amdgcn_update_dpp(lo, lo, 0x4E, 0xF, 0xF, false);
            phi = __builtin_amdgcn_update_dpp(hi, hi, 0x4E, 0xF, 0xF, false);
            break;
        default:
            plo = __builtin_amdgcn_update_dpp(lo, lo, 0x141, 0xF, 0xF, false);
            phi = __builtin_amdgcn_update_dpp(hi, hi, 0x141, 0xF, 0xF, false);
            break;
    }
    return ((u64)(unsigned)phi << 32) | (unsigned)plo;
}

// ---------------------------------------------------------------------------
// One pass over the IoU matrix, both reductions.
// Lanes own the 128 boxes (2/lane); each wave owns 64 anchors staged in LDS
// (uniform-address ds_reads, immediate offsets, zero per-iter address math).
// Row (per-anchor) reduce: per-lane packed key -> LDS transpose -> 8 lanes per
// anchor serial-reduce 8 entries + 3 quad-DPP u64 steps.
// Col (per-box): per-lane strict '>' over ascending anchors (jnp tie rules).
// ---------------------------------------------------------------------------
__global__ __launch_bounds__(256) void fused_kernel(
    const float4* __restrict__ anchors, const float4* __restrict__ bboxes,
    u64* __restrict__ rowkey,        // [NB][A_TOTAL] (iou_bits<<32)|(127-m)
    u64* __restrict__ colpart) {     // [NB][SPLIT][NM] (iou_bits<<32)|(~a)
#pragma clang fp contract(off)
    const int b = blockIdx.y, tid = threadIdx.x;
    const int lane = tid & 63, wv = tid >> 6;
    const int abase = (blockIdx.x * WPB + wv) * 64;

    __shared__ float4 s_anch[WPB][64];
    __shared__ float  s_area[WPB][64];
    __shared__ u64    s_row[WPB][CHUNK][65];   // pad 65: b64 reads at 4-way floor
    __shared__ float  s_cv[WPB][NM];
    __shared__ int    s_ca[WPB][NM];

    {   // stage + convert this wave's 64 anchors (wave-private region, no barrier)
        float4 an = anchors[abase + lane];
        float hw = an.z * 0.5f, hh = an.w * 0.5f;
        float x1 = an.x - hw, y1 = an.y - hh, x2 = an.x + hw, y2 = an.y + hh;
        s_anch[wv][lane] = make_float4(x1, y1, x2, y2);
        s_area[wv][lane] = (x2 - x1) * (y2 - y1);
    }

    float4 b0 = bboxes[b * NM + lane];          // m = lane
    float4 b1 = bboxes[b * NM + lane + 64];     // m = lane + 64
    float areaB0 = (b0.z - b0.x) * (b0.w - b0.y);
    float areaB1 = (b1.z - b1.x) * (b1.w - b1.y);

    float cv0 = -1.0f, cv1 = -1.0f;
    int ca0 = 0, ca1 = 0;
    const unsigned lo_c0 = 127u - (unsigned)lane;   // m = lane
    const unsigned lo_c1 = 63u - (unsigned)lane;    // m = lane + 64

    const int ia = lane >> 3, part = lane & 7;      // row-reduce assignment

    for (int c = 0; c < NCH; ++c) {
#pragma unroll
        for (int i = 0; i < CHUNK; ++i) {
            const int ii = c * CHUNK + i;
            const float4 ap = s_anch[wv][ii];       // uniform addr, imm offset
            const float areaA = s_area[wv][ii];

            float ltx0 = fmaxf(ap.x, b0.x), lty0 = fmaxf(ap.y, b0.y);
            float rbx0 = fminf(ap.z, b0.z), rby0 = fminf(ap.w, b0.w);
            float wx0 = fmaxf(rbx0 - ltx0, 0.0f), wy0 = fmaxf(rby0 - lty0, 0.0f);
            float in0 = wx0 * wy0;
            float iou0 = in0 / ((areaA + areaB0) - in0);

            float ltx1 = fmaxf(ap.x, b1.x), lty1 = fmaxf(ap.y, b1.y);
            float rbx1 = fminf(ap.z, b1.z), rby1 = fminf(ap.w, b1.w);
            float wx1 = fmaxf(rbx1 - ltx1, 0.0f), wy1 = fmaxf(rby1 - lty1, 0.0f);
            float in1 = wx1 * wy1;
            float iou1 = in1 / ((areaA + areaB1) - in1);

            const int a = abase + ii;
            if (iou0 > cv0) { cv0 = iou0; ca0 = a; }   // strict > : smallest a on tie
            if (iou1 > cv1) { cv1 = iou1; ca1 = a; }

            // per-lane winner of its 2 boxes; tie -> smaller m (lane)
            float wvv = fmaxf(iou0, iou1);
            unsigned lo = (iou1 > iou0) ? lo_c1 : lo_c0;
            s_row[wv][i][lane] = ((u64)__float_as_uint(wvv) << 32) | (u64)lo;
        }
        // reduce this chunk: 8 lanes per anchor, 8 serial entries each
        u64 k = 0ull;
#pragma unroll
        for (int t = 0; t < 8; ++t) {
            u64 o = s_row[wv][ia][part * 8 + t];
            if (o > k) k = o;
        }
        { u64 o = dpp_u64(k, 0xB1);  if (o > k) k = o; }   // xor 1 (quad)
        { u64 o = dpp_u64(k, 0x4E);  if (o > k) k = o; }   // xor 2 (quad)
        { u64 o = dpp_u64(k, 0x141); if (o > k) k = o; }   // half-row mirror
        if (part == 0)
            rowkey[(size_t)b * A_TOTAL + abase + c * CHUNK + ia] = k;
    }

    // block-level column reduce across the 4 waves (ascending anchor ranges)
    s_cv[wv][lane] = cv0;       s_ca[wv][lane] = ca0;
    s_cv[wv][lane + 64] = cv1;  s_ca[wv][lane + 64] = ca1;
    __syncthreads();
    if (tid < NM) {
        float bv = s_cv[0][tid]; int ba = s_ca[0][tid];
        for (int w = 1; w < WPB; ++w) {
            float ov = s_cv[w][tid];
            if (ov > bv) { bv = ov; ba = s_ca[w][tid]; }
        }
        colpart[((size_t)b * SPLIT + blockIdx.x) * NM + tid] =
            ((u64)__float_as_uint(bv) << 32) | (u64)(0xFFFFFFFFu - (unsigned)ba);
    }
}

// Final col reduce (512 thr: 4 groups x 42 splits) + parallel override table.
// "later gt wins" sequential scan == j wins iff no j' > j maps to same anchor.
__global__ __launch_bounds__(512) void colreduce_kernel(
    const u64* __restrict__ colpart, float* __restrict__ colmax,
    unsigned short* __restrict__ tbl) {
    const int b = blockIdx.x;
    const int m = threadIdx.x & 127, g = threadIdx.x >> 7;

    u64 k = 0ull;
    for (int s = g * 42; s < g * 42 + 42; ++s) {
        u64 o = colpart[((size_t)b * SPLIT + s) * NM + m];
        if (o > k) k = o;
    }
    __shared__ u64 sk[4][NM];
    __shared__ int sca[NM];
    sk[g][m] = k;
    __syncthreads();
    if (threadIdx.x < NM) {
        k = sk[0][m];
        for (int w = 1; w < 4; ++w) if (sk[w][m] > k) k = sk[w][m];
        colmax[b * NM + m] = __uint_as_float((unsigned)(k >> 32));
        sca[m] = (int)(0xFFFFFFFFu - (unsigned)(k & 0xFFFFFFFFull));
    }
    __syncthreads();
    if (threadIdx.x < NM) {
        const int my = sca[m];
        bool win = true;
        for (int j = m + 1; j < NM; ++j) win = win && (sca[j] != my);
        if (win) tbl[(size_t)b * A_TOTAL + my] = (unsigned short)m;
    }
}

// Streaming epilogue: override lookup + score + matched gather.
__global__ __launch_bounds__(256) void epilogue_kernel(
    const float4* __restrict__ bboxes, const int* __restrict__ labels,
    const float* __restrict__ colmax, const u64* __restrict__ rowkey,
    const unsigned short* __restrict__ tbl,
    float* __restrict__ out_scores, float4* __restrict__ out_matched) {
#pragma clang fp contract(off)
    const int b = blockIdx.y, tid = threadIdx.x;
    const int a = blockIdx.x * 256 + tid;       // A_TOTAL == 168*256

    __shared__ float4 sbox[NM];
    __shared__ float  s_cm[NM];
    __shared__ int    s_lab[NM];
    if (tid < NM) {
        sbox[tid]  = bboxes[b * NM + tid];
        s_cm[tid]  = colmax[b * NM + tid];
        s_lab[tid] = labels[b * NM + tid];
    }
    __syncthreads();

    u64 rk = rowkey[(size_t)b * A_TOTAL + a];
    float best = __uint_as_float((unsigned)(rk >> 32));
    int   bi   = 127 - (int)(rk & 0xFFFFFFFFull);

    unsigned short j = tbl[(size_t)b * A_TOTAL + a];
    if (j != 0xFFFFu) { bi = j; best = s_cm[j]; }

    float denom = fmaxf(s_cm[bi], 0.3f);        // IOU_THR
    float val   = (best < 0.15f) ? 0.0f : best; // IOU_THR * 0.5
    float score = val / denom;
    if (s_lab[bi] <= 0) score = 0.0f;

    out_scores[(size_t)b * A_TOTAL + a]  = score;
    out_matched[(size_t)b * A_TOTAL + a] = sbox[bi];
}

extern "C" void kernel_launch(void* const* d_in, const int* in_sizes, int n_in,
                              void* d_out, int out_size, void* d_ws, size_t ws_size,
                              hipStream_t stream) {
    const int*    labels  = (const int*)d_in[0];     // [NB, NM] int32
    const float4* bboxes  = (const float4*)d_in[1];  // [NB, NM, 4] xyxy
    const float4* anchors = (const float4*)d_in[2];  // [A_TOTAL, 4] cxcywh

    float* out = (float*)d_out;                      // scores [NB,A], matched [NB,A,4]

    char* ws = (char*)d_ws;
    u64*   rowkey  = (u64*)ws;                        ws += (size_t)NB * A_TOTAL * 8;
    u64*   colpart = (u64*)ws;                        ws += (size_t)NB * SPLIT * NM * 8;
    float* colmax  = (float*)ws;                      ws += (size_t)NB * NM * 4;
    unsigned short* tbl = (unsigned short*)ws;

    hipMemsetAsync(tbl, 0xFF, (size_t)NB * A_TOTAL * 2, stream);  // sentinel

    dim3 gF(SPLIT, NB);
    fused_kernel<<<gF, 256, 0, stream>>>(anchors, bboxes, rowkey, colpart);

    colreduce_kernel<<<NB, 512, 0, stream>>>(colpart, colmax, tbl);

    dim3 gE(A_TOTAL / 256, NB);
    epilogue_kernel<<<gE, 256, 0, stream>>>(
        bboxes, labels, colmax, rowkey, tbl,
        out, (float4*)(out + (size_t)NB * A_TOTAL));
}

// Round 5
// 150.481 us; speedup vs baseline: 1.4721x; 1.0325x over previous
//
#include <hip/hip_runtime.h>
#include <stdint.h>

typedef unsigned long long u64;

#define A_TOTAL 43008
#define NB 16
#define NM 128
#define SPLIT 168                 // blocks per batch; 4 waves/block; 64 anchors/wave
#define WPB 4

// wave-wide rotate-by-1-lane via DPP (gfx9-family wave_rol:1 = ctrl 0x134).
// Carry and anchor registers rotate with the SAME ctrl, so the scheme is
// rotation-direction-agnostic: each anchor's running-max slot always rides
// with its anchor data, visiting all 64 lanes exactly once over 64 iters.
__device__ __forceinline__ int rot1_i(int v) {
    return __builtin_amdgcn_update_dpp(v, v, 0x134, 0xF, 0xF, false);
}
__device__ __forceinline__ float rot1_f(float v) {
    return __int_as_float(rot1_i(__float_as_int(v)));
}
__device__ __forceinline__ u64 rot1_u64(u64 v) {
    unsigned lo = (unsigned)v, hi = (unsigned)(v >> 32);
    lo = (unsigned)rot1_i((int)lo);
    hi = (unsigned)rot1_i((int)hi);
    return ((u64)hi << 32) | lo;
}

// ---------------------------------------------------------------------------
// One pass over the IoU matrix, both reductions, zero LDS in the hot loop.
// Lanes own the 128 boxes (2/lane, fixed); anchors live in registers and
// rotate. Row (per-anchor) max: co-rotating packed u64 carry.
// Col (per-box) max: per-lane packed u64 (iou_bits<<32)|(~a) running max
// (low bits make smallest anchor index win on exact iou ties — jnp argmax).
// ---------------------------------------------------------------------------
__global__ __launch_bounds__(256) void fused_kernel(
    const float4* __restrict__ anchors, const float4* __restrict__ bboxes,
    u64* __restrict__ rowkey,        // [NB][A_TOTAL] (iou_bits<<32)|(127-m)
    u64* __restrict__ colfinal) {    // [NB][NM] global atomicMax table
#pragma clang fp contract(off)
    const int b = blockIdx.y, tid = threadIdx.x;
    const int lane = tid & 63, wv = tid >> 6;
    const int abase = (blockIdx.x * WPB + wv) * 64;

    // stage this lane's anchor in registers (rotates through the wave)
    float4 an = anchors[abase + lane];
    float hw = an.z * 0.5f, hh = an.w * 0.5f;
    float ax1 = an.x - hw, ay1 = an.y - hh;
    float ax2 = an.x + hw, ay2 = an.y + hh;
    float areaA = (ax2 - ax1) * (ay2 - ay1);
    int   aidx  = abase + lane;

    float4 b0 = bboxes[b * NM + lane];          // m = lane       (fixed)
    float4 b1 = bboxes[b * NM + lane + 64];     // m = lane + 64  (fixed)
    float areaB0 = (b0.z - b0.x) * (b0.w - b0.y);
    float areaB1 = (b1.z - b1.x) * (b1.w - b1.y);

    u64 carry = 0ull;                            // row slot (co-rotates)
    u64 ck0 = 0ull, ck1 = 0ull;                  // col running keys (fixed)
    const u64 mlo0 = (u64)(127u - (unsigned)lane);  // m = lane
    const u64 mlo1 = (u64)(63u  - (unsigned)lane);  // m = lane + 64

#pragma unroll 4
    for (int i = 0; i < 64; ++i) {
        float ltx0 = fmaxf(ax1, b0.x), lty0 = fmaxf(ay1, b0.y);
        float rbx0 = fminf(ax2, b0.z), rby0 = fminf(ay2, b0.w);
        float wx0 = fmaxf(rbx0 - ltx0, 0.0f), wy0 = fmaxf(rby0 - lty0, 0.0f);
        float in0 = wx0 * wy0;
        float iou0 = in0 / ((areaA + areaB0) - in0);

        float ltx1 = fmaxf(ax1, b1.x), lty1 = fmaxf(ay1, b1.y);
        float rbx1 = fminf(ax2, b1.z), rby1 = fminf(ay2, b1.w);
        float wx1 = fmaxf(rbx1 - ltx1, 0.0f), wy1 = fmaxf(rby1 - lty1, 0.0f);
        float in1 = wx1 * wy1;
        float iou1 = in1 / ((areaA + areaB1) - in1);

        // col (per-box) running max; ties -> smaller anchor via ~aidx low bits
        u64 k0 = ((u64)__float_as_uint(iou0) << 32) | (u64)(unsigned)(~aidx);
        u64 k1 = ((u64)__float_as_uint(iou1) << 32) | (u64)(unsigned)(~aidx);
        if (k0 > ck0) ck0 = k0;
        if (k1 > ck1) ck1 = k1;

        // row (per-anchor): merge this lane's 2 boxes into the co-rotating slot
        u64 r0 = ((u64)__float_as_uint(iou0) << 32) | mlo0;
        u64 r1 = ((u64)__float_as_uint(iou1) << 32) | mlo1;
        u64 rm = (r1 > r0) ? r1 : r0;            // tie -> r0 (smaller m) wins
        if (rm > carry) carry = rm;

        // rotate anchor + slot together (direction irrelevant, period 64)
        ax1 = rot1_f(ax1); ay1 = rot1_f(ay1);
        ax2 = rot1_f(ax2); ay2 = rot1_f(ay2);
        areaA = rot1_f(areaA); aidx = rot1_i(aidx);
        carry = rot1_u64(carry);
    }
    // after 64 merge+rotate steps every slot is back home: lane l owns anchor l
    rowkey[(size_t)b * A_TOTAL + abase + lane] = carry;

    // block-level column reduce across the 4 waves, then one atomic per box
    __shared__ u64 s_ck[WPB][NM];
    s_ck[wv][lane] = ck0;
    s_ck[wv][lane + 64] = ck1;
    __syncthreads();
    if (tid < NM) {
        u64 k = s_ck[0][tid];
        for (int w = 1; w < WPB; ++w) if (s_ck[w][tid] > k) k = s_ck[w][tid];
        atomicMax(&colfinal[b * NM + tid], k);
    }
}

// Streaming epilogue: per-block override window + score + matched gather.
// "later gt wins" sequential scan == largest j with colarg[j]==a, built here
// with an LDS atomicMax over this block's 256-anchor window (~0.76 hits/blk).
__global__ __launch_bounds__(256) void epilogue_kernel(
    const float4* __restrict__ bboxes, const int* __restrict__ labels,
    const u64* __restrict__ colfinal, const u64* __restrict__ rowkey,
    float* __restrict__ out_scores, float4* __restrict__ out_matched) {
#pragma clang fp contract(off)
    const int b = blockIdx.y, tid = threadIdx.x;
    const int a0 = blockIdx.x * 256, a = a0 + tid;   // A_TOTAL == 168*256

    __shared__ float4 sbox[NM];
    __shared__ float  s_cm[NM];
    __shared__ int    s_lab[NM];
    __shared__ int    ovr[256];
    ovr[tid] = -1;

    int my_ca = -1;
    if (tid < NM) {
        u64 k = colfinal[b * NM + tid];
        s_cm[tid] = __uint_as_float((unsigned)(k >> 32));
        my_ca = (int)~((unsigned)(k & 0xFFFFFFFFull));   // recover anchor idx
        sbox[tid]  = bboxes[b * NM + tid];
        s_lab[tid] = labels[b * NM + tid];
    }
    __syncthreads();
    if (tid < NM && my_ca >= a0 && my_ca < a0 + 256)
        atomicMax(&ovr[my_ca - a0], tid);                // later j wins == max j
    __syncthreads();

    u64 rk = rowkey[(size_t)b * A_TOTAL + a];
    float best = __uint_as_float((unsigned)(rk >> 32));
    int   bi   = 127 - (int)(rk & 0xFFFFFFFFull);

    int o = ovr[tid];
    if (o >= 0) { bi = o; best = s_cm[o]; }

    float denom = fmaxf(s_cm[bi], 0.3f);        // IOU_THR
    float val   = (best < 0.15f) ? 0.0f : best; // IOU_THR * 0.5
    float score = val / denom;
    if (s_lab[bi] <= 0) score = 0.0f;

    out_scores[(size_t)b * A_TOTAL + a]  = score;
    out_matched[(size_t)b * A_TOTAL + a] = sbox[bi];
}

extern "C" void kernel_launch(void* const* d_in, const int* in_sizes, int n_in,
                              void* d_out, int out_size, void* d_ws, size_t ws_size,
                              hipStream_t stream) {
    const int*    labels  = (const int*)d_in[0];     // [NB, NM] int32
    const float4* bboxes  = (const float4*)d_in[1];  // [NB, NM, 4] xyxy
    const float4* anchors = (const float4*)d_in[2];  // [A_TOTAL, 4] cxcywh

    float* out = (float*)d_out;                      // scores [NB,A], matched [NB,A,4]

    char* ws = (char*)d_ws;
    u64* rowkey   = (u64*)ws;                        ws += (size_t)NB * A_TOTAL * 8;
    u64* colfinal = (u64*)ws;

    hipMemsetAsync(colfinal, 0, (size_t)NB * NM * 8, stream);  // 16 KB

    dim3 g(SPLIT, NB);
    fused_kernel<<<g, 256, 0, stream>>>(anchors, bboxes, rowkey, colfinal);
    epilogue_kernel<<<g, 256, 0, stream>>>(
        bboxes, labels, colfinal, rowkey,
        out, (float4*)(out + (size_t)NB * A_TOTAL));
}

// Round 7
// 145.113 us; speedup vs baseline: 1.5266x; 1.0370x over previous
//
#include <hip/hip_runtime.h>
#include <stdint.h>

typedef unsigned long long u64;

#define A_TOTAL 43008
#define NB 16
#define NM 128
#define SPLIT 168                 // blocks per batch; 4 waves; 64 anchors/lane-wave
#define WPB 4

// u64 cross-lane DPP max-merge helper (pairs stay inside aligned 8-lane octets).
__device__ __forceinline__ u64 dpp_u64(u64 v, const int ctrl) {
    int lo = (int)(unsigned)v, hi = (int)(unsigned)(v >> 32);
    int plo, phi;
    switch (ctrl) {
        case 0xB1:   // quad_perm [1,0,3,2] : xor 1
            plo = __builtin_amdgcn_update_dpp(lo, lo, 0xB1, 0xF, 0xF, false);
            phi = __builtin_amdgcn_update_dpp(hi, hi, 0xB1, 0xF, 0xF, false);
            break;
        case 0x4E:   // quad_perm [2,3,0,1] : xor 2
            plo = __builtin_amdgcn_update_dpp(lo, lo, 0x4E, 0xF, 0xF, false);
            phi = __builtin_amdgcn_update_dpp(hi, hi, 0x4E, 0xF, 0xF, false);
            break;
        default:     // 0x141 row_half_mirror : p -> 7-p within octet (xor7 == xor4 here)
            plo = __builtin_amdgcn_update_dpp(lo, lo, 0x141, 0xF, 0xF, false);
            phi = __builtin_amdgcn_update_dpp(hi, hi, 0x141, 0xF, 0xF, false);
            break;
    }
    return ((u64)(unsigned)phi << 32) | (unsigned)plo;
}

// Tiny prep: bbox areas [NB*NM] + zero-init colfinal [NB*NM]. 8 blocks x 256.
__global__ __launch_bounds__(256) void prep_kernel(
    const float4* __restrict__ bboxes, float* __restrict__ areaBp,
    u64* __restrict__ colfinal) {
#pragma clang fp contract(off)
    const int i = blockIdx.x * 256 + threadIdx.x;    // 0..2047
    float4 v = bboxes[i];
    areaBp[i] = (v.z - v.x) * (v.w - v.y);
    colfinal[i] = 0ull;
}

// ---------------------------------------------------------------------------
// Fused IoU pass, lane = anchor / loop = box.
// Row (per-anchor) max/argmax: PRIVATE 3-inst update (m is wave-uniform SGPR).
// Box coords/areas: wave-uniform indices -> scalar s_loads, SGPR operands.
// Col (per-box): f32 LDS transpose per 8-box chunk (2-way banks = free),
// 8-entry serial (ascending t = ascending anchor, strict '>'), pack
// (iou<<32)|(~anchor), 3 DPP u64 merges across octets, stage per-wave,
// block-merge, one device atomicMax per box. All ties = jnp first-occurrence.
// ---------------------------------------------------------------------------
__global__ __launch_bounds__(256) void fused_kernel(
    const float4* __restrict__ anchors, const float* __restrict__ bb,
    const float* __restrict__ areaBp,
    u64* __restrict__ rowkey,        // [NB][A_TOTAL] (iou_bits<<32)|m
    u64* __restrict__ colfinal) {    // [NB][NM] atomicMax table
#pragma clang fp contract(off)
    const int b = blockIdx.y, tid = threadIdx.x;
    const int lane = tid & 63, wv = tid >> 6;
    const int abase = blockIdx.x * 256 + wv * 64;

    __shared__ float s_col[WPB][8][65];   // chunk transpose (2-way = free)
    __shared__ u64   s_ck[WPB][NM];       // per-wave col keys

    // this lane's anchor, converted once (amortized over 128 box-iters)
    float4 an = anchors[abase + lane];
    float hw = an.z * 0.5f, hh = an.w * 0.5f;
    float ax1 = an.x - hw, ay1 = an.y - hh;
    float ax2 = an.x + hw, ay2 = an.y + hh;
    float areaA = (ax2 - ax1) * (ay2 - ay1);

    const float* box  = bb + (size_t)b * NM * 4;      // uniform -> s_load
    const float* area = areaBp + (size_t)b * NM;

    float best_v = -1.0f; int best_m = 0;             // private row state
    const int bi = lane >> 3, part = lane & 7;
    const int rbase = part * 8;

    for (int c = 0; c < 16; ++c) {
#pragma unroll
        for (int i = 0; i < 8; ++i) {
            const int m = c * 8 + i;                   // wave-uniform
            const float bx1 = box[4 * m + 0], by1 = box[4 * m + 1];
            const float bx2 = box[4 * m + 2], by2 = box[4 * m + 3];
            const float areaB = area[m];

            float ltx = fmaxf(ax1, bx1), lty = fmaxf(ay1, by1);
            float rbx = fminf(ax2, bx2), rby = fminf(ay2, by2);
            float wx = fmaxf(rbx - ltx, 0.0f), wy = fmaxf(rby - lty, 0.0f);
            float inter = wx * wy;
            float iou = inter / ((areaA + areaB) - inter);

            if (iou > best_v) { best_v = iou; best_m = m; }  // first m on tie
            s_col[wv][i][lane] = iou;
        }
        // col chunk reduce: 8 lanes (parts) per box, 8 serial entries each
        float v = -1.0f; int tb = 0;
#pragma unroll
        for (int t = 0; t < 8; ++t) {                 // ascending anchor
            float o = s_col[wv][bi][rbase + t];
            if (o > v) { v = o; tb = t; }             // strict > : smallest t
        }
        unsigned aidx = (unsigned)(abase + rbase + tb);
        u64 key = ((u64)__float_as_uint(v) << 32) | (u64)(unsigned)(~aidx);
        { u64 o = dpp_u64(key, 0xB1);  if (o > key) key = o; }
        { u64 o = dpp_u64(key, 0x4E);  if (o > key) key = o; }
        { u64 o = dpp_u64(key, 0x141); if (o > key) key = o; }
        if (part == 0) s_ck[wv][c * 8 + bi] = key;
    }

    rowkey[(size_t)b * A_TOTAL + abase + lane] =
        ((u64)__float_as_uint(best_v) << 32) | (u64)(unsigned)best_m;

    __syncthreads();
    if (tid < NM) {
        u64 k = s_ck[0][tid];
        for (int w = 1; w < WPB; ++w) if (s_ck[w][tid] > k) k = s_ck[w][tid];
        atomicMax(&colfinal[b * NM + tid], k);
    }
}

// Streaming epilogue (R5-proven): per-block override window + score + gather.
__global__ __launch_bounds__(256) void epilogue_kernel(
    const float4* __restrict__ bboxes, const int* __restrict__ labels,
    const u64* __restrict__ colfinal, const u64* __restrict__ rowkey,
    float* __restrict__ out_scores, float4* __restrict__ out_matched) {
#pragma clang fp contract(off)
    const int b = blockIdx.y, tid = threadIdx.x;
    const int a0 = blockIdx.x * 256, a = a0 + tid;   // A_TOTAL == 168*256

    __shared__ float4 sbox[NM];
    __shared__ float  s_cm[NM];
    __shared__ int    s_lab[NM];
    __shared__ int    ovr[256];
    ovr[tid] = -1;

    int my_ca = -1;
    if (tid < NM) {
        u64 k = colfinal[b * NM + tid];
        s_cm[tid] = __uint_as_float((unsigned)(k >> 32));
        my_ca = ~((int)(unsigned)(k & 0xFFFFFFFFull));   // recover anchor idx
        sbox[tid]  = bboxes[b * NM + tid];
        s_lab[tid] = labels[b * NM + tid];
    }
    __syncthreads();
    if (tid < NM && my_ca >= a0 && my_ca < a0 + 256)
        atomicMax(&ovr[my_ca - a0], tid);                // later j wins == max j
    __syncthreads();

    u64 rk = rowkey[(size_t)b * A_TOTAL + a];
    float best = __uint_as_float((unsigned)(rk >> 32));
    int   bi   = (int)(rk & 0xFFFFFFFFull);

    int o = ovr[tid];
    if (o >= 0) { bi = o; best = s_cm[o]; }

    float denom = fmaxf(s_cm[bi], 0.3f);        // IOU_THR
    float val   = (best < 0.15f) ? 0.0f : best; // IOU_THR * 0.5
    float score = val / denom;
    if (s_lab[bi] <= 0) score = 0.0f;

    out_scores[(size_t)b * A_TOTAL + a]  = score;
    out_matched[(size_t)b * A_TOTAL + a] = sbox[bi];
}

extern "C" void kernel_launch(void* const* d_in, const int* in_sizes, int n_in,
                              void* d_out, int out_size, void* d_ws, size_t ws_size,
                              hipStream_t stream) {
    const int*    labels  = (const int*)d_in[0];     // [NB, NM] int32
    const float4* bboxes  = (const float4*)d_in[1];  // [NB, NM, 4] xyxy
    const float4* anchors = (const float4*)d_in[2];  // [A_TOTAL, 4] cxcywh

    float* out = (float*)d_out;                      // scores [NB,A], matched [NB,A,4]

    char* ws = (char*)d_ws;
    u64*   rowkey   = (u64*)ws;                      ws += (size_t)NB * A_TOTAL * 8;
    u64*   colfinal = (u64*)ws;                      ws += (size_t)NB * NM * 8;
    float* areaBp   = (float*)ws;

    prep_kernel<<<(NB * NM) / 256, 256, 0, stream>>>(bboxes, areaBp, colfinal);

    dim3 g(SPLIT, NB);
    fused_kernel<<<g, 256, 0, stream>>>(anchors, (const float*)bboxes, areaBp,
                                        rowkey, colfinal);
    epilogue_kernel<<<g, 256, 0, stream>>>(
        bboxes, labels, colfinal, rowkey,
        out, (float4*)(out + (size_t)NB * A_TOTAL));
}

// Round 8
// 129.964 us; speedup vs baseline: 1.7045x; 1.1166x over previous
//
#include <hip/hip_runtime.h>
#include <stdint.h>

typedef unsigned long long u64;

#define A_TOTAL 43008
#define NB 16
#define NM 128
#define SPLIT 168                 // blocks per batch; 4 waves; 64 anchors/lane-wave
#define WPB 4

// Bit-exact fp32 division via Markstein sequence: v_rcp + 2 Newton + residual
// correction, all full-rate fmas. Correctly rounded (== v_div result) for
// normal-range operands: here num in [0, ~1e5], den in [~64, ~4e5]; num==0
// yields exactly 0. Avoids the ~50-cycle div_scale/div_fmas/div_fixup chain.
__device__ __forceinline__ float exact_div(float x, float y) {
    float r;
    asm("v_rcp_f32 %0, %1" : "=v"(r) : "v"(y));
    float e  = __builtin_fmaf(-y, r, 1.0f);
    r        = __builtin_fmaf(e, r, r);
    e        = __builtin_fmaf(-y, r, 1.0f);
    r        = __builtin_fmaf(e, r, r);
    float q  = x * r;
    float rs = __builtin_fmaf(-y, q, x);
    return __builtin_fmaf(rs, r, q);
}

// u64 cross-lane DPP max-merge helper (pairs stay inside aligned 8-lane octets).
__device__ __forceinline__ u64 dpp_u64(u64 v, const int ctrl) {
    int lo = (int)(unsigned)v, hi = (int)(unsigned)(v >> 32);
    int plo, phi;
    switch (ctrl) {
        case 0xB1:   // quad_perm [1,0,3,2] : xor 1
            plo = __builtin_amdgcn_update_dpp(lo, lo, 0xB1, 0xF, 0xF, false);
            phi = __builtin_amdgcn_update_dpp(hi, hi, 0xB1, 0xF, 0xF, false);
            break;
        case 0x4E:   // quad_perm [2,3,0,1] : xor 2
            plo = __builtin_amdgcn_update_dpp(lo, lo, 0x4E, 0xF, 0xF, false);
            phi = __builtin_amdgcn_update_dpp(hi, hi, 0x4E, 0xF, 0xF, false);
            break;
        default:     // 0x141 row_half_mirror : p -> 7-p within octet
            plo = __builtin_amdgcn_update_dpp(lo, lo, 0x141, 0xF, 0xF, false);
            phi = __builtin_amdgcn_update_dpp(hi, hi, 0x141, 0xF, 0xF, false);
            break;
    }
    return ((u64)(unsigned)phi << 32) | (unsigned)plo;
}

// Tiny prep: bbox areas [NB*NM] + zero-init colfinal [NB*NM]. 8 blocks x 256.
__global__ __launch_bounds__(256) void prep_kernel(
    const float4* __restrict__ bboxes, float* __restrict__ areaBp,
    u64* __restrict__ colfinal) {
#pragma clang fp contract(off)
    const int i = blockIdx.x * 256 + threadIdx.x;    // 0..2047
    float4 v = bboxes[i];
    areaBp[i] = (v.z - v.x) * (v.w - v.y);
    colfinal[i] = 0ull;
}

// ---------------------------------------------------------------------------
// Fused IoU pass, lane = anchor / loop = box (R7 structure, exact_div inner).
// Row (per-anchor) max/argmax: PRIVATE 3-inst update (m is wave-uniform SGPR).
// Box coords/areas: wave-uniform indices -> scalar s_loads, SGPR operands.
// Col (per-box): f32 LDS transpose per 8-box chunk (2-way banks = free),
// 8-entry serial (ascending t = ascending anchor, strict '>'), pack
// (iou<<32)|(~anchor), 3 DPP u64 merges across octets, stage per-wave,
// block-merge, one device atomicMax per box. All ties = jnp first-occurrence.
// ---------------------------------------------------------------------------
__global__ __launch_bounds__(256) void fused_kernel(
    const float4* __restrict__ anchors, const float* __restrict__ bb,
    const float* __restrict__ areaBp,
    u64* __restrict__ rowkey,        // [NB][A_TOTAL] (iou_bits<<32)|m
    u64* __restrict__ colfinal) {    // [NB][NM] atomicMax table
#pragma clang fp contract(off)
    const int b = blockIdx.y, tid = threadIdx.x;
    const int lane = tid & 63, wv = tid >> 6;
    const int abase = blockIdx.x * 256 + wv * 64;

    __shared__ float s_col[WPB][8][65];   // chunk transpose (2-way = free)
    __shared__ u64   s_ck[WPB][NM];       // per-wave col keys

    // this lane's anchor, converted once (amortized over 128 box-iters)
    float4 an = anchors[abase + lane];
    float hw = an.z * 0.5f, hh = an.w * 0.5f;
    float ax1 = an.x - hw, ay1 = an.y - hh;
    float ax2 = an.x + hw, ay2 = an.y + hh;
    float areaA = (ax2 - ax1) * (ay2 - ay1);

    const float* box  = bb + (size_t)b * NM * 4;      // uniform -> s_load
    const float* area = areaBp + (size_t)b * NM;

    float best_v = -1.0f; int best_m = 0;             // private row state
    const int bi = lane >> 3, part = lane & 7;
    const int rbase = part * 8;

    for (int c = 0; c < 16; ++c) {
#pragma unroll
        for (int i = 0; i < 8; ++i) {
            const int m = c * 8 + i;                   // wave-uniform
            const float bx1 = box[4 * m + 0], by1 = box[4 * m + 1];
            const float bx2 = box[4 * m + 2], by2 = box[4 * m + 3];
            const float areaB = area[m];

            float ltx = fmaxf(ax1, bx1), lty = fmaxf(ay1, by1);
            float rbx = fminf(ax2, bx2), rby = fminf(ay2, by2);
            float wx = fmaxf(rbx - ltx, 0.0f), wy = fmaxf(rby - lty, 0.0f);
            float inter = wx * wy;
            float iou = exact_div(inter, (areaA + areaB) - inter);

            if (iou > best_v) { best_v = iou; best_m = m; }  // first m on tie
            s_col[wv][i][lane] = iou;
        }
        // col chunk reduce: 8 lanes (parts) per box, 8 serial entries each
        float v = -1.0f; int tb = 0;
#pragma unroll
        for (int t = 0; t < 8; ++t) {                 // ascending anchor
            float o = s_col[wv][bi][rbase + t];
            if (o > v) { v = o; tb = t; }             // strict > : smallest t
        }
        unsigned aidx = (unsigned)(abase + rbase + tb);
        u64 key = ((u64)__float_as_uint(v) << 32) | (u64)(unsigned)(~aidx);
        { u64 o = dpp_u64(key, 0xB1);  if (o > key) key = o; }
        { u64 o = dpp_u64(key, 0x4E);  if (o > key) key = o; }
        { u64 o = dpp_u64(key, 0x141); if (o > key) key = o; }
        if (part == 0) s_ck[wv][c * 8 + bi] = key;
    }

    rowkey[(size_t)b * A_TOTAL + abase + lane] =
        ((u64)__float_as_uint(best_v) << 32) | (u64)(unsigned)best_m;

    __syncthreads();
    if (tid < NM) {
        u64 k = s_ck[0][tid];
        for (int w = 1; w < WPB; ++w) if (s_ck[w][tid] > k) k = s_ck[w][tid];
        atomicMax(&colfinal[b * NM + tid], k);
    }
}

// Streaming epilogue (R5-proven): per-block override window + score + gather.
__global__ __launch_bounds__(256) void epilogue_kernel(
    const float4* __restrict__ bboxes, const int* __restrict__ labels,
    const u64* __restrict__ colfinal, const u64* __restrict__ rowkey,
    float* __restrict__ out_scores, float4* __restrict__ out_matched) {
#pragma clang fp contract(off)
    const int b = blockIdx.y, tid = threadIdx.x;
    const int a0 = blockIdx.x * 256, a = a0 + tid;   // A_TOTAL == 168*256

    __shared__ float4 sbox[NM];
    __shared__ float  s_cm[NM];
    __shared__ int    s_lab[NM];
    __shared__ int    ovr[256];
    ovr[tid] = -1;

    int my_ca = -1;
    if (tid < NM) {
        u64 k = colfinal[b * NM + tid];
        s_cm[tid] = __uint_as_float((unsigned)(k >> 32));
        my_ca = ~((int)(unsigned)(k & 0xFFFFFFFFull));   // recover anchor idx
        sbox[tid]  = bboxes[b * NM + tid];
        s_lab[tid] = labels[b * NM + tid];
    }
    __syncthreads();
    if (tid < NM && my_ca >= a0 && my_ca < a0 + 256)
        atomicMax(&ovr[my_ca - a0], tid);                // later j wins == max j
    __syncthreads();

    u64 rk = rowkey[(size_t)b * A_TOTAL + a];
    float best = __uint_as_float((unsigned)(rk >> 32));
    int   bi   = (int)(rk & 0xFFFFFFFFull);

    int o = ovr[tid];
    if (o >= 0) { bi = o; best = s_cm[o]; }

    float denom = fmaxf(s_cm[bi], 0.3f);        // IOU_THR
    float val   = (best < 0.15f) ? 0.0f : best; // IOU_THR * 0.5
    float score = val / denom;
    if (s_lab[bi] <= 0) score = 0.0f;

    out_scores[(size_t)b * A_TOTAL + a]  = score;
    out_matched[(size_t)b * A_TOTAL + a] = sbox[bi];
}

extern "C" void kernel_launch(void* const* d_in, const int* in_sizes, int n_in,
                              void* d_out, int out_size, void* d_ws, size_t ws_size,
                              hipStream_t stream) {
    const int*    labels  = (const int*)d_in[0];     // [NB, NM] int32
    const float4* bboxes  = (const float4*)d_in[1];  // [NB, NM, 4] xyxy
    const float4* anchors = (const float4*)d_in[2];  // [A_TOTAL, 4] cxcywh

    float* out = (float*)d_out;                      // scores [NB,A], matched [NB,A,4]

    char* ws = (char*)d_ws;
    u64*   rowkey   = (u64*)ws;                      ws += (size_t)NB * A_TOTAL * 8;
    u64*   colfinal = (u64*)ws;                      ws += (size_t)NB * NM * 8;
    float* areaBp   = (float*)ws;

    prep_kernel<<<(NB * NM) / 256, 256, 0, stream>>>(bboxes, areaBp, colfinal);

    dim3 g(SPLIT, NB);
    fused_kernel<<<g, 256, 0, stream>>>(anchors, (const float*)bboxes, areaBp,
                                        rowkey, colfinal);
    epilogue_kernel<<<g, 256, 0, stream>>>(
        bboxes, labels, colfinal, rowkey,
        out, (float4*)(out + (size_t)NB * A_TOTAL));
}